// Round 8
// baseline (507.589 us; speedup 1.0000x reference)
//
#include <hip/hip_runtime.h>
#include <hip/hip_fp16.h>

#define NN 50000
#define EE 800000
#define HIDD 96
#define NZ 384   // BATCH*NUM_ZONES

// ---------- CSR build ----------
__global__ void k_deg(const int* __restrict__ dst, int* __restrict__ deg){
  int e=blockIdx.x*blockDim.x+threadIdx.x;
  if(e>=EE) return;
  atomicAdd(&deg[dst[e]],1);
}

__global__ void k_scan1(const int* __restrict__ deg, int* __restrict__ off, int* __restrict__ part){
  __shared__ int sd[256];
  int t=threadIdx.x, b=blockIdx.x;
  int base=b*1024+t*4;
  int v0=(base+0<NN)?deg[base+0]:0;
  int v1=(base+1<NN)?deg[base+1]:0;
  int v2=(base+2<NN)?deg[base+2]:0;
  int v3=(base+3<NN)?deg[base+3]:0;
  int s=v0+v1+v2+v3;
  sd[t]=s; __syncthreads();
  for(int o=1;o<256;o<<=1){
    int x=(t>=o)?sd[t-o]:0;
    __syncthreads();
    sd[t]+=x;
    __syncthreads();
  }
  int ep=sd[t]-s;
  if(base+0<NN) off[base+0]=ep;
  if(base+1<NN) off[base+1]=ep+v0;
  if(base+2<NN) off[base+2]=ep+v0+v1;
  if(base+3<NN) off[base+3]=ep+v0+v1+v2;
  if(t==255) part[b]=sd[255];
}

__global__ void k_scan2(int* part, int* off, int nb){
  if(threadIdx.x==0&&blockIdx.x==0){
    int run=0;
    for(int i=0;i<nb;i++){ int x=part[i]; part[i]=run; run+=x; }
    off[NN]=run;
  }
}

__global__ void k_scan3(const int* __restrict__ part, int* __restrict__ off, int* __restrict__ cur){
  int i=blockIdx.x*blockDim.x+threadIdx.x;
  if(i<NN){ int v=off[i]+part[i>>10]; off[i]=v; cur[i]=v; }
}

// scatter ONE 8B record per edge: {src, edge_id}
__global__ void k_scatter(const int* __restrict__ src, const int* __restrict__ dst,
                          int* __restrict__ cur, int2* __restrict__ sie){
  int e=blockIdx.x*blockDim.x+threadIdx.x;
  if(e>=EE) return;
  int d=dst[e];
  int p=atomicAdd(&cur[d],1);
  sie[p]=int2{src[e],e};
}

// ---------- eattr -> fp16 table ----------
__global__ void k_ea16(const float* __restrict__ ea, __half* __restrict__ o){
  int i=blockIdx.x*blockDim.x+threadIdx.x;
  if(i>=EE*2) return;
  float2 v=*(const float2*)(ea+(size_t)i*2);
  *(__half2*)(o+(size_t)i*2)=__floats2half2_rn(v.x,v.y);
}

// ---------- weight prep: Watt[l][96][8] fp32, M = We.a_edge ----------
__global__ void k_prepw(const float* __restrict__ conv_w, const float* __restrict__ a_src,
                        const float* __restrict__ a_dst, const float* __restrict__ lin_e,
                        const float* __restrict__ a_e,
                        float* __restrict__ Watt, float* __restrict__ Mm){
  int t=blockIdx.x*blockDim.x+threadIdx.x;
  const int WT=4*96*8;
  if(t<WT){
    int l=t/(96*8); int rem=t-l*(96*8); int k=rem>>3; int j=rem&7;
    int hh=j&3;
    const float* W=conv_w+(size_t)l*96*96+(size_t)k*96;
    const float* a=((j>=4)?a_dst:a_src)+l*96+hh*24;
    float v=0.f;
    #pragma unroll
    for(int c=0;c<24;c++) v+=W[hh*24+c]*a[c];
    Watt[t]=v;
  } else if(t<WT+64){
    int q=t-WT; int l=q>>4; int i=(q>>2)&3; int hh=q&3;
    const float* We=lin_e+(size_t)l*4*96+(size_t)i*96;
    const float* a=a_e+l*96+hh*24;
    float v=0.f;
    #pragma unroll
    for(int c=0;c<24;c++) v+=We[hh*24+c]*a[c];
    Mm[q]=v;  // M[l][i][h]
  }
}

// ---------- input MLP layer 1 ----------
__global__ void k_mlp1(const float* __restrict__ x, const float* __restrict__ w,
                       const float* __restrict__ b, float* __restrict__ out){
  int i=blockIdx.x*blockDim.x+threadIdx.x;
  if(i>=NN) return;
  float xv[12];
  #pragma unroll
  for(int k=0;k<12;k++) xv[k]=x[(size_t)i*12+k];
  for(int j=0;j<HIDD;j++){
    float a=b[j];
    #pragma unroll
    for(int k=0;k<12;k++) a+=xv[k]*w[k*HIDD+j];
    out[(size_t)i*HIDD+j]=fmaxf(a,0.f);
  }
}

// ---------- GEMM: C[N][96] = A[N][96] @ W[96][96] (+bias), fp32 or fp16 out ----------
template<bool H16>
__global__ __launch_bounds__(256) void k_gemm96(const float* __restrict__ A, int lda,
                                                const float* __restrict__ W,
                                                const float* __restrict__ bias,
                                                void* __restrict__ Cv, int ldc){
  __shared__ float As[64][100];
  __shared__ float Ws[96][96];
  int t=threadIdx.x;
  int r0=blockIdx.x*64;
  for(int i=t;i<96*96/4;i+=256) ((float4*)&Ws[0][0])[i]=((const float4*)W)[i];
  for(int i=t;i<64*24;i+=256){
    int rr=i/24, cc=(i-rr*24)*4; int g=r0+rr;
    float4 v = (g<NN)? *(const float4*)(A+(size_t)g*lda+cc) : float4{0.f,0.f,0.f,0.f};
    *(float4*)&As[rr][cc]=v;
  }
  __syncthreads();
  int cg=t&15, rg=t>>4;
  int c0=cg*6, r=rg*4;
  float acc[4][6];
  #pragma unroll
  for(int i=0;i<4;i++)
    #pragma unroll
    for(int j=0;j<6;j++) acc[i][j]=0.f;
  for(int k4=0;k4<96;k4+=4){
    float4 a0=*(float4*)&As[r  ][k4];
    float4 a1=*(float4*)&As[r+1][k4];
    float4 a2=*(float4*)&As[r+2][k4];
    float4 a3=*(float4*)&As[r+3][k4];
    #pragma unroll
    for(int kk=0;kk<4;kk++){
      float2 w01=*(float2*)&Ws[k4+kk][c0];
      float2 w23=*(float2*)&Ws[k4+kk][c0+2];
      float2 w45=*(float2*)&Ws[k4+kk][c0+4];
      float wv[6]={w01.x,w01.y,w23.x,w23.y,w45.x,w45.y};
      float av0=((float*)&a0)[kk],av1=((float*)&a1)[kk],av2=((float*)&a2)[kk],av3=((float*)&a3)[kk];
      #pragma unroll
      for(int j=0;j<6;j++){
        acc[0][j]+=av0*wv[j];
        acc[1][j]+=av1*wv[j];
        acc[2][j]+=av2*wv[j];
        acc[3][j]+=av3*wv[j];
      }
    }
  }
  #pragma unroll
  for(int i=0;i<4;i++){
    int g=r0+r+i;
    if(g<NN){
      if(H16){
        __half* C=(__half*)Cv;
        #pragma unroll
        for(int jp=0;jp<3;jp++){
          __half2 pk=__floats2half2_rn(acc[i][2*jp],acc[i][2*jp+1]);
          *(__half2*)(C+(size_t)g*ldc+c0+2*jp)=pk;
        }
      }else{
        float* C=(float*)Cv;
        #pragma unroll
        for(int j=0;j<6;j++) C[(size_t)g*ldc+c0+j]=acc[i][j]+(bias?bias[c0+j]:0.f);
      }
    }
  }
}

// ---------- attention logit columns (layer 0 only): att[n][0..8) = h[n][:] @ W8[96][8] ----------
__global__ __launch_bounds__(256) void k_att8(const float* __restrict__ h, const float* __restrict__ W8,
                                              float* __restrict__ att){
  __shared__ float ws[96*8];
  int t=threadIdx.x;
  for(int i=t;i<768;i+=256) ws[i]=W8[i];
  __syncthreads();
  int n=blockIdx.x*256+t;
  if(n>=NN) return;
  float acc[8];
  #pragma unroll
  for(int j=0;j<8;j++) acc[j]=0.f;
  for(int k4=0;k4<24;k4++){
    float4 v=*(const float4*)(h+(size_t)n*96+k4*4);
    #pragma unroll
    for(int kk=0;kk<4;kk++){
      float a=((float*)&v)[kk];
      #pragma unroll
      for(int j=0;j<8;j++) acc[j]+=a*ws[(k4*4+kk)*8+j];
    }
  }
  #pragma unroll
  for(int j=0;j<8;j++) att[(size_t)n*8+j]=acc[j];
}

// ---------- fused GAT agg (no-max softmax) + self-loop + bias + ELU + residual + LN
//            + next-layer att logits (written to a SEPARATE buffer: no cross-block race) ----------
// 16-lane subgroup per node; block = 256 threads = 16 nodes.
__global__ __launch_bounds__(256) void k_agg(const __half* __restrict__ hp16,
    const float* __restrict__ att, float* __restrict__ h,
    const int* __restrict__ off, const int2* __restrict__ sie, const __half* __restrict__ ea16,
    const float* __restrict__ Mm, const float* __restrict__ bias,
    const float* __restrict__ nsc, const float* __restrict__ nbi,
    const float* __restrict__ WaNext, float* __restrict__ attNext){
  __shared__ float w4[16][17][4];
  __shared__ int   roA[16][17];
  int tid=threadIdx.x;
  int sg=tid>>4, sl=tid&15;
  int n=blockIdx.x*16+sg;
  if(n>=NN) return;
  float M[16];
  #pragma unroll
  for(int i=0;i<16;i++) M[i]=Mm[i];
  const float4 ad=*(const float4*)(att+(size_t)n*8+4);
  int b0=off[n], deg=off[n+1]-b0;
  float invdeg=1.f/(float)(deg>0?deg:1);
  int hL=sl>>2;
  int sloff=sl*12;
  float ds0=0.f,ds1=0.f,ds2=0.f,ds3=0.f;
  float sx=0.f,sy=0.f,sz=0.f,sw=0.f;
  float acc[6]={0.f,0.f,0.f,0.f,0.f,0.f};
  const char* hb=(const char*)hp16;

  for(int cs=0;cs<deg;cs+=16){
    int idx=cs+sl;
    bool valid=idx<deg;
    float w0=0.f,w1=0.f,w2=0.f,w3=0.f; int ro=0;
    if(valid){
      int ei=b0+idx;
      int2 se=sie[ei];
      int s=se.x;
      ro=s*192;
      uint2 ue=*(const uint2*)(ea16+(size_t)se.y*4);
      float2 e01=__half22float2(*(__half2*)&ue.x);
      float2 e23=__half22float2(*(__half2*)&ue.y);
      sx+=e01.x; sy+=e01.y; sz+=e23.x; sw+=e23.y;
      const float4 as=*(const float4*)(att+(size_t)s*8);
      float a0=as.x+ad.x+e01.x*M[0]+e01.y*M[4]+e23.x*M[8] +e23.y*M[12];
      float a1=as.y+ad.y+e01.x*M[1]+e01.y*M[5]+e23.x*M[9] +e23.y*M[13];
      float a2=as.z+ad.z+e01.x*M[2]+e01.y*M[6]+e23.x*M[10]+e23.y*M[14];
      float a3=as.w+ad.w+e01.x*M[3]+e01.y*M[7]+e23.x*M[11]+e23.y*M[15];
      a0=a0>0.f?a0:0.2f*a0; a1=a1>0.f?a1:0.2f*a1;
      a2=a2>0.f?a2:0.2f*a2; a3=a3>0.f?a3:0.2f*a3;
      w0=__expf(a0); w1=__expf(a1); w2=__expf(a2); w3=__expf(a3);
      ds0+=w0; ds1+=w1; ds2+=w2; ds3+=w3;
    }
    *(float4*)&w4[sg][sl][0]=float4{w0,w1,w2,w3};
    roA[sg][sl]=ro;
    int nc=deg-cs; if(nc>16) nc=16;
    if(nc>0){
      float ev0=w4[sg][0][hL];
      uint3 u0=*(const uint3*)(hb+(size_t)(unsigned)roA[sg][0]+sloff);
      for(int j=1;j<nc;j++){
        float ev1=w4[sg][j][hL];
        uint3 u1=*(const uint3*)(hb+(size_t)(unsigned)roA[sg][j]+sloff);
        float2 f0=__half22float2(*(__half2*)&u0.x);
        float2 f1=__half22float2(*(__half2*)&u0.y);
        float2 f2=__half22float2(*(__half2*)&u0.z);
        acc[0]+=ev0*f0.x; acc[1]+=ev0*f0.y;
        acc[2]+=ev0*f1.x; acc[3]+=ev0*f1.y;
        acc[4]+=ev0*f2.x; acc[5]+=ev0*f2.y;
        ev0=ev1; u0=u1;
      }
      float2 f0=__half22float2(*(__half2*)&u0.x);
      float2 f1=__half22float2(*(__half2*)&u0.y);
      float2 f2=__half22float2(*(__half2*)&u0.z);
      acc[0]+=ev0*f0.x; acc[1]+=ev0*f0.y;
      acc[2]+=ev0*f1.x; acc[3]+=ev0*f1.y;
      acc[4]+=ev0*f2.x; acc[5]+=ev0*f2.y;
    }
  }
  // 16-lane reductions (denominators + edge-attr sums)
  #pragma unroll
  for(int m=1;m<16;m<<=1){
    ds0+=__shfl_xor(ds0,m); ds1+=__shfl_xor(ds1,m);
    ds2+=__shfl_xor(ds2,m); ds3+=__shfl_xor(ds3,m);
    sx +=__shfl_xor(sx ,m); sy +=__shfl_xor(sy ,m);
    sz +=__shfl_xor(sz ,m); sw +=__shfl_xor(sw ,m);
  }
  // self-loop with mean edge-attr
  float lx=sx*invdeg, ly=sy*invdeg, lz=sz*invdeg, lw=sw*invdeg;
  const float4 aself=*(const float4*)(att+(size_t)n*8);
  float b0a=aself.x+ad.x+lx*M[0]+ly*M[4]+lz*M[8] +lw*M[12];
  float b1a=aself.y+ad.y+lx*M[1]+ly*M[5]+lz*M[9] +lw*M[13];
  float b2a=aself.z+ad.z+lx*M[2]+ly*M[6]+lz*M[10]+lw*M[14];
  float b3a=aself.w+ad.w+lx*M[3]+ly*M[7]+lz*M[11]+lw*M[15];
  b0a=b0a>0.f?b0a:0.2f*b0a; b1a=b1a>0.f?b1a:0.2f*b1a;
  b2a=b2a>0.f?b2a:0.2f*b2a; b3a=b3a>0.f?b3a:0.2f*b3a;
  float e0=__expf(b0a),e1=__expf(b1a),e2=__expf(b2a),e3=__expf(b3a);
  ds0+=e0; ds1+=e1; ds2+=e2; ds3+=e3;
  float eL=(hL==0)?e0:((hL==1)?e1:((hL==2)?e2:e3));
  {
    const char* rp=hb+(size_t)n*192+sloff;
    uint3 u=*(const uint3*)rp;
    float2 f0=__half22float2(*(__half2*)&u.x);
    float2 f1=__half22float2(*(__half2*)&u.y);
    float2 f2=__half22float2(*(__half2*)&u.z);
    acc[0]+=eL*f0.x; acc[1]+=eL*f0.y;
    acc[2]+=eL*f1.x; acc[3]+=eL*f1.y;
    acc[4]+=eL*f2.x; acc[5]+=eL*f2.y;
  }
  // epilogue: /den + bias -> ELU -> +residual -> LayerNorm (16-lane)
  float dL=(hL==0)?ds0:((hL==1)?ds1:((hL==2)?ds2:ds3));
  float rinv=1.f/(dL+1e-16f);
  const float* hrow=h+(size_t)n*HIDD+(size_t)sl*6;
  float2 r01=*(const float2*)(hrow);
  float2 r23=*(const float2*)(hrow+2);
  float2 r45=*(const float2*)(hrow+4);
  float rr[6]={r01.x,r01.y,r23.x,r23.y,r45.x,r45.y};
  const float* bp=bias+sl*6;
  float t[6];
  #pragma unroll
  for(int c=0;c<6;c++){
    float v=acc[c]*rinv+bp[c];
    v=v>0.f?v:expm1f(v);
    t[c]=v+rr[c];
  }
  float s1l=t[0]+t[1]+t[2]+t[3]+t[4]+t[5];
  float s2l=t[0]*t[0]+t[1]*t[1]+t[2]*t[2]+t[3]*t[3]+t[4]*t[4]+t[5]*t[5];
  #pragma unroll
  for(int m=1;m<16;m<<=1){ s1l+=__shfl_xor(s1l,m); s2l+=__shfl_xor(s2l,m); }
  float mean=s1l*(1.f/96.f);
  float var=s2l*(1.f/96.f)-mean*mean;
  float rs=rsqrtf(var+1e-5f);
  float* op=h+(size_t)n*HIDD+(size_t)sl*6;
  const float* sc=nsc+sl*6;
  const float* bi=nbi+sl*6;
  float o[6];
  #pragma unroll
  for(int c=0;c<6;c++) o[c]=(t[c]-mean)*rs*sc[c]+bi[c];
  *(float2*)(op)  =float2{o[0],o[1]};
  *(float2*)(op+2)=float2{o[2],o[3]};
  *(float2*)(op+4)=float2{o[4],o[5]};
  // ---- fused next-layer att logits into the OTHER buffer ----
  if(WaNext){
    float pj[8]={0.f,0.f,0.f,0.f,0.f,0.f,0.f,0.f};
    const float* wb=WaNext+(size_t)(sl*6)*8;
    #pragma unroll
    for(int c=0;c<6;c++){
      float4 wlo=*(const float4*)(wb+c*8);
      float4 whi=*(const float4*)(wb+c*8+4);
      pj[0]+=o[c]*wlo.x; pj[1]+=o[c]*wlo.y; pj[2]+=o[c]*wlo.z; pj[3]+=o[c]*wlo.w;
      pj[4]+=o[c]*whi.x; pj[5]+=o[c]*whi.y; pj[6]+=o[c]*whi.z; pj[7]+=o[c]*whi.w;
    }
    #pragma unroll
    for(int m=1;m<16;m<<=1){
      #pragma unroll
      for(int j=0;j<8;j++) pj[j]+=__shfl_xor(pj[j],m);
    }
    if(sl<8){
      float v=(sl==0)?pj[0]:(sl==1)?pj[1]:(sl==2)?pj[2]:(sl==3)?pj[3]
             :(sl==4)?pj[4]:(sl==5)?pj[5]:(sl==6)?pj[6]:pj[7];
      attNext[(size_t)n*8+sl]=v;
    }
  }
}

// ---------- prediction heads ----------
__global__ __launch_bounds__(256) void k_hd1(const float* __restrict__ h, const int* __restrict__ zone,
    const float* __restrict__ cw1,const float* __restrict__ cb1,
    const float* __restrict__ dw1,const float* __restrict__ db1,
    const float* __restrict__ jw1,const float* __restrict__ jb1,
    float* __restrict__ t1){
  int idx=blockIdx.x*256+threadIdx.x;
  if(idx>=3*NZ*96) return;
  int hd=idx/(NZ*96); int rem=idx-hd*(NZ*96); int row=rem/96; int j=rem-row*96;
  const float* w1=(hd==0)?cw1:((hd==1)?dw1:jw1);
  const float* b1=(hd==0)?cb1:((hd==1)?db1:jb1);
  int n=zone[row];
  const float* hr=h+(size_t)n*96;
  float acc=b1[j];
  #pragma unroll
  for(int k4=0;k4<24;k4++){
    float4 hv=*(const float4*)(hr+k4*4);
    acc+=hv.x*w1[(k4*4+0)*96+j];
    acc+=hv.y*w1[(k4*4+1)*96+j];
    acc+=hv.z*w1[(k4*4+2)*96+j];
    acc+=hv.w*w1[(k4*4+3)*96+j];
  }
  t1[idx]=fmaxf(acc,0.f);
}

__global__ __launch_bounds__(256) void k_hd2(const float* __restrict__ t1,
    const float* __restrict__ cw2,const float* __restrict__ cb2,
    const float* __restrict__ dw2,const float* __restrict__ db2,
    const float* __restrict__ jw2,const float* __restrict__ jb2,
    float* __restrict__ t2){
  int idx=blockIdx.x*256+threadIdx.x;
  if(idx>=3*NZ*48) return;
  int hd=idx/(NZ*48); int rem=idx-hd*(NZ*48); int row=rem/48; int c=rem-row*48;
  const float* w2=(hd==0)?cw2:((hd==1)?dw2:jw2);
  const float* b2=(hd==0)?cb2:((hd==1)?db2:jb2);
  const float* t1r=t1+(size_t)hd*NZ*96+(size_t)row*96;
  float acc=b2[c];
  #pragma unroll
  for(int k4=0;k4<24;k4++){
    float4 tv=*(const float4*)(t1r+k4*4);
    acc+=tv.x*w2[(k4*4+0)*48+c];
    acc+=tv.y*w2[(k4*4+1)*48+c];
    acc+=tv.z*w2[(k4*4+2)*48+c];
    acc+=tv.w*w2[(k4*4+3)*48+c];
  }
  t2[idx]=fmaxf(acc,0.f);
}

__global__ __launch_bounds__(256) void k_hd3(const float* __restrict__ t2,
    const float* __restrict__ cw3,const float* __restrict__ cb3,
    const float* __restrict__ dw3,const float* __restrict__ db3,
    const float* __restrict__ jw3,const float* __restrict__ jb3,
    float* __restrict__ out){
  int idx=blockIdx.x*256+threadIdx.x;
  if(idx>=NZ*4) return;
  int row=idx>>2, o=idx&3;
  int hd=(o<2)?0:((o==2)?1:2);
  int c=(o<2)?o:0;
  int osz=(hd==0)?2:1;
  const float* w3=(hd==0)?cw3:((hd==1)?dw3:jw3);
  const float* b3=(hd==0)?cb3:((hd==1)?db3:jb3);
  const float* t2r=t2+(size_t)hd*NZ*48+(size_t)row*48;
  float acc=b3[c];
  #pragma unroll
  for(int k=0;k<48;k++) acc+=t2r[k]*w3[k*osz+c];
  out[idx]=acc;
}

extern "C" void kernel_launch(void* const* d_in, const int* in_sizes, int n_in,
                              void* d_out, int out_size, void* d_ws, size_t ws_size,
                              hipStream_t stream){
  const float* x       =(const float*)d_in[0];
  const int*   eidx    =(const int*)  d_in[1];
  const float* eattr   =(const float*)d_in[2];
  const int*   zone    =(const int*)  d_in[3];
  const float* in_w1   =(const float*)d_in[4];
  const float* in_b1   =(const float*)d_in[5];
  const float* in_w2   =(const float*)d_in[6];
  const float* in_b2   =(const float*)d_in[7];
  const float* conv_w  =(const float*)d_in[8];
  const float* att_src =(const float*)d_in[9];
  const float* att_dst =(const float*)d_in[10];
  const float* lin_edge=(const float*)d_in[11];
  const float* att_edge=(const float*)d_in[12];
  const float* conv_bias=(const float*)d_in[13];
  const float* nsc     =(const float*)d_in[14];
  const float* nbi     =(const float*)d_in[15];
  float* out=(float*)d_out;

  char* p=(char*)d_ws;
  auto carve=[&](size_t bytes)->char*{ char* r=p; p+=(bytes+255)&~(size_t)255; return r; };
  float*  h    =(float*)carve((size_t)NN*96*4);
  char*   uni  =carve((size_t)NN*96*4);              // union: hid1 fp32 | {hp16, attA, attB}
  float*  hid1 =(float*)uni;
  __half* hp16 =(__half*)uni;                         // NN*96*2 = 9.6 MB
  float*  attA =(float*)(uni+(size_t)NN*96*2);        // NN*8*4  = 1.6 MB
  float*  attB =(float*)(uni+(size_t)NN*96*2+(size_t)NN*8*4);
  int2*   sie  =(int2*) carve((size_t)EE*8);
  __half* ea16 =(__half*)carve((size_t)EE*4*2);
  int*    deg  =(int*)  carve((size_t)NN*4);
  int*    off  =(int*)  carve((size_t)(NN+1)*4);
  int*    cur  =(int*)  carve((size_t)NN*4);
  float*  Watt =(float*)carve((size_t)4*96*8*4);
  float*  Mm   =(float*)carve(64*4);
  int*    part =(int*)  carve(64*4);
  float*  t1b  =(float*)carve((size_t)3*NZ*96*4);
  float*  t2b  =(float*)carve((size_t)3*NZ*48*4);

  const int* srcp=eidx;
  const int* dstp=eidx+EE;

  hipMemsetAsync(deg,0,(size_t)NN*4,stream);
  k_deg<<<EE/256,256,0,stream>>>(dstp,deg);
  k_scan1<<<49,256,0,stream>>>(deg,off,part);
  k_scan2<<<1,64,0,stream>>>(part,off,49);
  k_scan3<<<(NN+255)/256,256,0,stream>>>(part,off,cur);
  k_scatter<<<EE/256,256,0,stream>>>(srcp,dstp,cur,sie);
  k_ea16<<<(EE*2+255)/256,256,0,stream>>>(eattr,ea16);
  k_prepw<<<(4*96*8+64+255)/256,256,0,stream>>>(conv_w,att_src,att_dst,lin_edge,att_edge,Watt,Mm);

  k_mlp1<<<(NN+255)/256,256,0,stream>>>(x,in_w1,in_b1,hid1);
  k_gemm96<false><<<(NN+63)/64,256,0,stream>>>(hid1,96,in_w2,in_b2,h,96);
  k_att8<<<(NN+255)/256,256,0,stream>>>(h,Watt,attA);

  for(int l=0;l<4;l++){
    k_gemm96<true><<<(NN+63)/64,256,0,stream>>>(h,96,conv_w+(size_t)l*96*96,nullptr,hp16,96);
    const float* att_in =(l&1)?attB:attA;
    float*       att_out=(l&1)?attA:attB;
    const float* WaNext=(l<3)?(Watt+(size_t)(l+1)*96*8):nullptr;
    k_agg<<<(NN+15)/16,256,0,stream>>>(hp16,att_in,h,off,sie,ea16,Mm+l*16,
                                       conv_bias+l*96,nsc+l*96,nbi+l*96,WaNext,att_out);
  }

  k_hd1<<<(3*NZ*96+255)/256,256,0,stream>>>(h,zone,
    (const float*)d_in[16],(const float*)d_in[17],
    (const float*)d_in[22],(const float*)d_in[23],
    (const float*)d_in[28],(const float*)d_in[29], t1b);
  k_hd2<<<(3*NZ*48+255)/256,256,0,stream>>>(t1b,
    (const float*)d_in[18],(const float*)d_in[19],
    (const float*)d_in[24],(const float*)d_in[25],
    (const float*)d_in[30],(const float*)d_in[31], t2b);
  k_hd3<<<(NZ*4+255)/256,256,0,stream>>>(t2b,
    (const float*)d_in[20],(const float*)d_in[21],
    (const float*)d_in[26],(const float*)d_in[27],
    (const float*)d_in[32],(const float*)d_in[33], out);
}

// Round 9
// 371.666 us; speedup vs baseline: 1.3657x; 1.3657x over previous
//
#include <hip/hip_runtime.h>
#include <hip/hip_fp16.h>

#define NN 50000
#define EE 800000
#define HIDD 96
#define NZ 384   // BATCH*NUM_ZONES

typedef __attribute__((ext_vector_type(8))) _Float16 half8;
typedef __attribute__((ext_vector_type(4))) float floatx4;

struct __align__(16) Rec{ int src; int pad; float4 ea; };   // 32 B

// ---------- CSR build ----------
__global__ void k_deg(const int* __restrict__ dst, int* __restrict__ deg){
  int e=blockIdx.x*blockDim.x+threadIdx.x;
  if(e>=EE) return;
  atomicAdd(&deg[dst[e]],1);
}

__global__ void k_scan1(const int* __restrict__ deg, int* __restrict__ off, int* __restrict__ part){
  __shared__ int sd[256];
  int t=threadIdx.x, b=blockIdx.x;
  int base=b*1024+t*4;
  int v0=(base+0<NN)?deg[base+0]:0;
  int v1=(base+1<NN)?deg[base+1]:0;
  int v2=(base+2<NN)?deg[base+2]:0;
  int v3=(base+3<NN)?deg[base+3]:0;
  int s=v0+v1+v2+v3;
  sd[t]=s; __syncthreads();
  for(int o=1;o<256;o<<=1){
    int x=(t>=o)?sd[t-o]:0;
    __syncthreads();
    sd[t]+=x;
    __syncthreads();
  }
  int ep=sd[t]-s;
  if(base+0<NN) off[base+0]=ep;
  if(base+1<NN) off[base+1]=ep+v0;
  if(base+2<NN) off[base+2]=ep+v0+v1;
  if(base+3<NN) off[base+3]=ep+v0+v1+v2;
  if(t==255) part[b]=sd[255];
}

__global__ void k_scan2(int* part, int* off, int nb){
  if(threadIdx.x==0&&blockIdx.x==0){
    int run=0;
    for(int i=0;i<nb;i++){ int x=part[i]; part[i]=run; run+=x; }
    off[NN]=run;
  }
}

__global__ void k_scan3(const int* __restrict__ part, int* __restrict__ off, int* __restrict__ cur){
  int i=blockIdx.x*blockDim.x+threadIdx.x;
  if(i<NN){ int v=off[i]+part[i>>10]; off[i]=v; cur[i]=v; }
}

// scatter ONE 32B record per edge: {src, pad, edge_attr}
__global__ void k_scatter(const int* __restrict__ src, const int* __restrict__ dst,
                          const float* __restrict__ eattr, int* __restrict__ cur,
                          Rec* __restrict__ rec){
  int e=blockIdx.x*blockDim.x+threadIdx.x;
  if(e>=EE) return;
  int d=dst[e];
  int p=atomicAdd(&cur[d],1);
  Rec r; r.src=src[e]; r.pad=0; r.ea=*(const float4*)(eattr+(size_t)e*4);
  rec[p]=r;
}

// ---------- weight prep: Watt[l][96][8] fp32, M = We.a_edge ----------
__global__ void k_prepw(const float* __restrict__ conv_w, const float* __restrict__ a_src,
                        const float* __restrict__ a_dst, const float* __restrict__ lin_e,
                        const float* __restrict__ a_e,
                        float* __restrict__ Watt, float* __restrict__ Mm){
  int t=blockIdx.x*blockDim.x+threadIdx.x;
  const int WT=4*96*8;
  if(t<WT){
    int l=t/(96*8); int rem=t-l*(96*8); int k=rem>>3; int j=rem&7;
    int hh=j&3;
    const float* W=conv_w+(size_t)l*96*96+(size_t)k*96;
    const float* a=((j>=4)?a_dst:a_src)+l*96+hh*24;
    float v=0.f;
    #pragma unroll
    for(int c=0;c<24;c++) v+=W[hh*24+c]*a[c];
    Watt[t]=v;
  } else if(t<WT+64){
    int q=t-WT; int l=q>>4; int i=(q>>2)&3; int hh=q&3;
    const float* We=lin_e+(size_t)l*4*96+(size_t)i*96;
    const float* a=a_e+l*96+hh*24;
    float v=0.f;
    #pragma unroll
    for(int c=0;c<24;c++) v+=We[hh*24+c]*a[c];
    Mm[q]=v;  // M[l][i][h]
  }
}

// ---------- input MLP layer 1 ----------
__global__ void k_mlp1(const float* __restrict__ x, const float* __restrict__ w,
                       const float* __restrict__ b, float* __restrict__ out){
  int i=blockIdx.x*blockDim.x+threadIdx.x;
  if(i>=NN) return;
  float xv[12];
  #pragma unroll
  for(int k=0;k<12;k++) xv[k]=x[(size_t)i*12+k];
  for(int j=0;j<HIDD;j++){
    float a=b[j];
    #pragma unroll
    for(int k=0;k<12;k++) a+=xv[k]*w[k*HIDD+j];
    out[(size_t)i*HIDD+j]=fmaxf(a,0.f);
  }
}

// ---------- fp32 GEMM (input MLP layer 2 only): C[N][96]=A[N][96]@W+bias ----------
__global__ __launch_bounds__(256) void k_gemm96(const float* __restrict__ A,
                                                const float* __restrict__ W,
                                                const float* __restrict__ bias,
                                                float* __restrict__ C){
  __shared__ float As[64][100];
  __shared__ float Ws[96][96];
  int t=threadIdx.x;
  int r0=blockIdx.x*64;
  for(int i=t;i<96*96/4;i+=256) ((float4*)&Ws[0][0])[i]=((const float4*)W)[i];
  for(int i=t;i<64*24;i+=256){
    int rr=i/24, cc=(i-rr*24)*4; int g=r0+rr;
    float4 v = (g<NN)? *(const float4*)(A+(size_t)g*96+cc) : float4{0.f,0.f,0.f,0.f};
    *(float4*)&As[rr][cc]=v;
  }
  __syncthreads();
  int cg=t&15, rg=t>>4;
  int c0=cg*6, r=rg*4;
  float acc[4][6];
  #pragma unroll
  for(int i=0;i<4;i++)
    #pragma unroll
    for(int j=0;j<6;j++) acc[i][j]=0.f;
  for(int k4=0;k4<96;k4+=4){
    float4 a0=*(float4*)&As[r  ][k4];
    float4 a1=*(float4*)&As[r+1][k4];
    float4 a2=*(float4*)&As[r+2][k4];
    float4 a3=*(float4*)&As[r+3][k4];
    #pragma unroll
    for(int kk=0;kk<4;kk++){
      float2 w01=*(float2*)&Ws[k4+kk][c0];
      float2 w23=*(float2*)&Ws[k4+kk][c0+2];
      float2 w45=*(float2*)&Ws[k4+kk][c0+4];
      float wv[6]={w01.x,w01.y,w23.x,w23.y,w45.x,w45.y};
      float av0=((float*)&a0)[kk],av1=((float*)&a1)[kk],av2=((float*)&a2)[kk],av3=((float*)&a3)[kk];
      #pragma unroll
      for(int j=0;j<6;j++){
        acc[0][j]+=av0*wv[j];
        acc[1][j]+=av1*wv[j];
        acc[2][j]+=av2*wv[j];
        acc[3][j]+=av3*wv[j];
      }
    }
  }
  #pragma unroll
  for(int i=0;i<4;i++){
    int g=r0+r+i;
    if(g<NN){
      #pragma unroll
      for(int j=0;j<6;j++) C[(size_t)g*96+c0+j]=acc[i][j]+bias[c0+j];
    }
  }
}

// ---------- MFMA projection GEMM: [hp16 | att] = A[N][96] @ [W 96x96 | Watt 96x8] ----------
// 256 thr = 4 waves; wave w handles rows block*64 + w*16 .. +15, all 112 cols (7 n-tiles).
// mfma_f32_16x16x32_f16; fragment layouts (m89/m97-verified, dtype-independent):
//   A: lane l holds row (l&15), k = (l>>4)*8 + j  (8 contiguous K)
//   B: lane l holds col (l&15), k = (l>>4)*8 + j
//   D: lane l reg r -> row (l>>4)*4 + r, col (l&15)
__global__ __launch_bounds__(256) void k_gemmM(const float* __restrict__ A,
    const float* __restrict__ W, const float* __restrict__ Watt8,
    __half* __restrict__ hp16, float* __restrict__ att){
  __shared__ half8 Bl[3][7][64];   // 21504 B, pre-swizzled to fragment layout
  int t=threadIdx.x;
  for(int i=t;i<3*7*64;i+=256){
    int kk=i/448; int rem=i-kk*448; int nb=rem>>6; int l=rem&63;
    int kbase=kk*32+((l>>4)<<3);
    int n=nb*16+(l&15);
    half8 v;
    #pragma unroll
    for(int j=0;j<8;j++){
      int k=kbase+j;
      float x=(n<96)?W[k*96+n]:((n<104)?Watt8[k*8+(n-96)]:0.f);
      v[j]=(_Float16)x;
    }
    Bl[kk][nb][l]=v;
  }
  __syncthreads();
  int wid=t>>6, l=t&63;
  int row0=blockIdx.x*64+wid*16;
  int arow=row0+(l&15);
  bool rv=arow<NN;
  const float* Ar=A+(size_t)(rv?arow:0)*96;
  half8 a[3];
  #pragma unroll
  for(int kk=0;kk<3;kk++){
    int kb=kk*32+((l>>4)<<3);
    floatx4 lo=*(const floatx4*)(Ar+kb);
    floatx4 hi=*(const floatx4*)(Ar+kb+4);
    half8 v;
    #pragma unroll
    for(int j=0;j<4;j++){ v[j]=(_Float16)(rv?lo[j]:0.f); v[j+4]=(_Float16)(rv?hi[j]:0.f); }
    a[kk]=v;
  }
  int col16=l&15;
  int rbase=row0+((l>>4)<<2);
  #pragma unroll
  for(int nb=0;nb<7;nb++){
    floatx4 acc={0.f,0.f,0.f,0.f};
    #pragma unroll
    for(int kk=0;kk<3;kk++)
      acc=__builtin_amdgcn_mfma_f32_16x16x32_f16(a[kk],Bl[kk][nb][l],acc,0,0,0);
    int col=nb*16+col16;
    if(col<96){
      #pragma unroll
      for(int r=0;r<4;r++){
        int g=rbase+r;
        if(g<NN) hp16[(size_t)g*96+col]=__float2half(acc[r]);
      }
    } else if(col<104){
      #pragma unroll
      for(int r=0;r<4;r++){
        int g=rbase+r;
        if(g<NN) att[(size_t)g*8+(col-96)]=acc[r];
      }
    }
  }
}

// ---------- fused GAT agg (no-max softmax) + self-loop + bias + ELU + residual + LN ----------
// 16-lane subgroup per node; block = 256 threads = 16 nodes.
__global__ __launch_bounds__(256) void k_agg(const __half* __restrict__ hp16,
    const float* __restrict__ att, float* __restrict__ h,
    const int* __restrict__ off, const Rec* __restrict__ rec,
    const float* __restrict__ Mm, const float* __restrict__ bias,
    const float* __restrict__ nsc, const float* __restrict__ nbi){
  __shared__ float w4[16][17][4];
  __shared__ int   roA[16][17];
  int tid=threadIdx.x;
  int sg=tid>>4, sl=tid&15;
  int n=blockIdx.x*16+sg;
  if(n>=NN) return;
  float M[16];
  #pragma unroll
  for(int i=0;i<16;i++) M[i]=Mm[i];
  const float4 ad=*(const float4*)(att+(size_t)n*8+4);
  int b0=off[n], deg=off[n+1]-b0;
  float invdeg=1.f/(float)(deg>0?deg:1);
  int hL=sl>>2;
  int sloff=sl*12;
  float ds0=0.f,ds1=0.f,ds2=0.f,ds3=0.f;
  float sx=0.f,sy=0.f,sz=0.f,sw=0.f;
  float acc[6]={0.f,0.f,0.f,0.f,0.f,0.f};
  const char* hb=(const char*)hp16;

  for(int cs=0;cs<deg;cs+=16){
    int idx=cs+sl;
    bool valid=idx<deg;
    float w0=0.f,w1=0.f,w2=0.f,w3=0.f; int ro=0;
    if(valid){
      int ei=b0+idx;
      int s=rec[ei].src;
      float4 ea=rec[ei].ea;
      ro=s*192;
      sx+=ea.x; sy+=ea.y; sz+=ea.z; sw+=ea.w;
      const float4 as=*(const float4*)(att+(size_t)s*8);
      float a0=as.x+ad.x+ea.x*M[0]+ea.y*M[4]+ea.z*M[8] +ea.w*M[12];
      float a1=as.y+ad.y+ea.x*M[1]+ea.y*M[5]+ea.z*M[9] +ea.w*M[13];
      float a2=as.z+ad.z+ea.x*M[2]+ea.y*M[6]+ea.z*M[10]+ea.w*M[14];
      float a3=as.w+ad.w+ea.x*M[3]+ea.y*M[7]+ea.z*M[11]+ea.w*M[15];
      a0=a0>0.f?a0:0.2f*a0; a1=a1>0.f?a1:0.2f*a1;
      a2=a2>0.f?a2:0.2f*a2; a3=a3>0.f?a3:0.2f*a3;
      w0=__expf(a0); w1=__expf(a1); w2=__expf(a2); w3=__expf(a3);
      ds0+=w0; ds1+=w1; ds2+=w2; ds3+=w3;
    }
    *(float4*)&w4[sg][sl][0]=float4{w0,w1,w2,w3};
    roA[sg][sl]=ro;
    int nc=deg-cs; if(nc>16) nc=16;
    if(nc>0){
      float ev0=w4[sg][0][hL];
      uint3 u0=*(const uint3*)(hb+(size_t)(unsigned)roA[sg][0]+sloff);
      for(int j=1;j<nc;j++){
        float ev1=w4[sg][j][hL];
        uint3 u1=*(const uint3*)(hb+(size_t)(unsigned)roA[sg][j]+sloff);
        float2 f0=__half22float2(*(__half2*)&u0.x);
        float2 f1=__half22float2(*(__half2*)&u0.y);
        float2 f2=__half22float2(*(__half2*)&u0.z);
        acc[0]+=ev0*f0.x; acc[1]+=ev0*f0.y;
        acc[2]+=ev0*f1.x; acc[3]+=ev0*f1.y;
        acc[4]+=ev0*f2.x; acc[5]+=ev0*f2.y;
        ev0=ev1; u0=u1;
      }
      float2 f0=__half22float2(*(__half2*)&u0.x);
      float2 f1=__half22float2(*(__half2*)&u0.y);
      float2 f2=__half22float2(*(__half2*)&u0.z);
      acc[0]+=ev0*f0.x; acc[1]+=ev0*f0.y;
      acc[2]+=ev0*f1.x; acc[3]+=ev0*f1.y;
      acc[4]+=ev0*f2.x; acc[5]+=ev0*f2.y;
    }
  }
  // 16-lane reductions (denominators + edge-attr sums)
  #pragma unroll
  for(int m=1;m<16;m<<=1){
    ds0+=__shfl_xor(ds0,m); ds1+=__shfl_xor(ds1,m);
    ds2+=__shfl_xor(ds2,m); ds3+=__shfl_xor(ds3,m);
    sx +=__shfl_xor(sx ,m); sy +=__shfl_xor(sy ,m);
    sz +=__shfl_xor(sz ,m); sw +=__shfl_xor(sw ,m);
  }
  // self-loop with mean edge-attr
  float lx=sx*invdeg, ly=sy*invdeg, lz=sz*invdeg, lw=sw*invdeg;
  const float4 aself=*(const float4*)(att+(size_t)n*8);
  float b0a=aself.x+ad.x+lx*M[0]+ly*M[4]+lz*M[8] +lw*M[12];
  float b1a=aself.y+ad.y+lx*M[1]+ly*M[5]+lz*M[9] +lw*M[13];
  float b2a=aself.z+ad.z+lx*M[2]+ly*M[6]+lz*M[10]+lw*M[14];
  float b3a=aself.w+ad.w+lx*M[3]+ly*M[7]+lz*M[11]+lw*M[15];
  b0a=b0a>0.f?b0a:0.2f*b0a; b1a=b1a>0.f?b1a:0.2f*b1a;
  b2a=b2a>0.f?b2a:0.2f*b2a; b3a=b3a>0.f?b3a:0.2f*b3a;
  float e0=__expf(b0a),e1=__expf(b1a),e2=__expf(b2a),e3=__expf(b3a);
  ds0+=e0; ds1+=e1; ds2+=e2; ds3+=e3;
  float eL=(hL==0)?e0:((hL==1)?e1:((hL==2)?e2:e3));
  {
    const char* rp=hb+(size_t)n*192+sloff;
    uint3 u=*(const uint3*)rp;
    float2 f0=__half22float2(*(__half2*)&u.x);
    float2 f1=__half22float2(*(__half2*)&u.y);
    float2 f2=__half22float2(*(__half2*)&u.z);
    acc[0]+=eL*f0.x; acc[1]+=eL*f0.y;
    acc[2]+=eL*f1.x; acc[3]+=eL*f1.y;
    acc[4]+=eL*f2.x; acc[5]+=eL*f2.y;
  }
  // epilogue: /den + bias -> ELU -> +residual -> LayerNorm (16-lane)
  float dL=(hL==0)?ds0:((hL==1)?ds1:((hL==2)?ds2:ds3));
  float rinv=1.f/(dL+1e-16f);
  const float* hrow=h+(size_t)n*HIDD+(size_t)sl*6;
  float2 r01=*(const float2*)(hrow);
  float2 r23=*(const float2*)(hrow+2);
  float2 r45=*(const float2*)(hrow+4);
  float rr[6]={r01.x,r01.y,r23.x,r23.y,r45.x,r45.y};
  const float* bp=bias+sl*6;
  float t[6];
  #pragma unroll
  for(int c=0;c<6;c++){
    float v=acc[c]*rinv+bp[c];
    v=v>0.f?v:expm1f(v);
    t[c]=v+rr[c];
  }
  float s1l=t[0]+t[1]+t[2]+t[3]+t[4]+t[5];
  float s2l=t[0]*t[0]+t[1]*t[1]+t[2]*t[2]+t[3]*t[3]+t[4]*t[4]+t[5]*t[5];
  #pragma unroll
  for(int m=1;m<16;m<<=1){ s1l+=__shfl_xor(s1l,m); s2l+=__shfl_xor(s2l,m); }
  float mean=s1l*(1.f/96.f);
  float var=s2l*(1.f/96.f)-mean*mean;
  float rs=rsqrtf(var+1e-5f);
  float* op=h+(size_t)n*HIDD+(size_t)sl*6;
  const float* sc=nsc+sl*6;
  const float* bi=nbi+sl*6;
  float o[6];
  #pragma unroll
  for(int c=0;c<6;c++) o[c]=(t[c]-mean)*rs*sc[c]+bi[c];
  *(float2*)(op)  =float2{o[0],o[1]};
  *(float2*)(op+2)=float2{o[2],o[3]};
  *(float2*)(op+4)=float2{o[4],o[5]};
}

// ---------- prediction heads ----------
__global__ __launch_bounds__(256) void k_hd1(const float* __restrict__ h, const int* __restrict__ zone,
    const float* __restrict__ cw1,const float* __restrict__ cb1,
    const float* __restrict__ dw1,const float* __restrict__ db1,
    const float* __restrict__ jw1,const float* __restrict__ jb1,
    float* __restrict__ t1){
  int idx=blockIdx.x*256+threadIdx.x;
  if(idx>=3*NZ*96) return;
  int hd=idx/(NZ*96); int rem=idx-hd*(NZ*96); int row=rem/96; int j=rem-row*96;
  const float* w1=(hd==0)?cw1:((hd==1)?dw1:jw1);
  const float* b1=(hd==0)?cb1:((hd==1)?db1:jb1);
  int n=zone[row];
  const float* hr=h+(size_t)n*96;
  float acc=b1[j];
  #pragma unroll
  for(int k4=0;k4<24;k4++){
    float4 hv=*(const float4*)(hr+k4*4);
    acc+=hv.x*w1[(k4*4+0)*96+j];
    acc+=hv.y*w1[(k4*4+1)*96+j];
    acc+=hv.z*w1[(k4*4+2)*96+j];
    acc+=hv.w*w1[(k4*4+3)*96+j];
  }
  t1[idx]=fmaxf(acc,0.f);
}

__global__ __launch_bounds__(256) void k_hd2(const float* __restrict__ t1,
    const float* __restrict__ cw2,const float* __restrict__ cb2,
    const float* __restrict__ dw2,const float* __restrict__ db2,
    const float* __restrict__ jw2,const float* __restrict__ jb2,
    float* __restrict__ t2){
  int idx=blockIdx.x*256+threadIdx.x;
  if(idx>=3*NZ*48) return;
  int hd=idx/(NZ*48); int rem=idx-hd*(NZ*48); int row=rem/48; int c=rem-row*48;
  const float* w2=(hd==0)?cw2:((hd==1)?dw2:jw2);
  const float* b2=(hd==0)?cb2:((hd==1)?db2:jb2);
  const float* t1r=t1+(size_t)hd*NZ*96+(size_t)row*96;
  float acc=b2[c];
  #pragma unroll
  for(int k4=0;k4<24;k4++){
    float4 tv=*(const float4*)(t1r+k4*4);
    acc+=tv.x*w2[(k4*4+0)*48+c];
    acc+=tv.y*w2[(k4*4+1)*48+c];
    acc+=tv.z*w2[(k4*4+2)*48+c];
    acc+=tv.w*w2[(k4*4+3)*48+c];
  }
  t2[idx]=fmaxf(acc,0.f);
}

__global__ __launch_bounds__(256) void k_hd3(const float* __restrict__ t2,
    const float* __restrict__ cw3,const float* __restrict__ cb3,
    const float* __restrict__ dw3,const float* __restrict__ db3,
    const float* __restrict__ jw3,const float* __restrict__ jb3,
    float* __restrict__ out){
  int idx=blockIdx.x*256+threadIdx.x;
  if(idx>=NZ*4) return;
  int row=idx>>2, o=idx&3;
  int hd=(o<2)?0:((o==2)?1:2);
  int c=(o<2)?o:0;
  int osz=(hd==0)?2:1;
  const float* w3=(hd==0)?cw3:((hd==1)?dw3:jw3);
  const float* b3=(hd==0)?cb3:((hd==1)?db3:jb3);
  const float* t2r=t2+(size_t)hd*NZ*48+(size_t)row*48;
  float acc=b3[c];
  #pragma unroll
  for(int k=0;k<48;k++) acc+=t2r[k]*w3[k*osz+c];
  out[idx]=acc;
}

extern "C" void kernel_launch(void* const* d_in, const int* in_sizes, int n_in,
                              void* d_out, int out_size, void* d_ws, size_t ws_size,
                              hipStream_t stream){
  const float* x       =(const float*)d_in[0];
  const int*   eidx    =(const int*)  d_in[1];
  const float* eattr   =(const float*)d_in[2];
  const int*   zone    =(const int*)  d_in[3];
  const float* in_w1   =(const float*)d_in[4];
  const float* in_b1   =(const float*)d_in[5];
  const float* in_w2   =(const float*)d_in[6];
  const float* in_b2   =(const float*)d_in[7];
  const float* conv_w  =(const float*)d_in[8];
  const float* att_src =(const float*)d_in[9];
  const float* att_dst =(const float*)d_in[10];
  const float* lin_edge=(const float*)d_in[11];
  const float* att_edge=(const float*)d_in[12];
  const float* conv_bias=(const float*)d_in[13];
  const float* nsc     =(const float*)d_in[14];
  const float* nbi     =(const float*)d_in[15];
  float* out=(float*)d_out;

  char* p=(char*)d_ws;
  auto carve=[&](size_t bytes)->char*{ char* r=p; p+=(bytes+255)&~(size_t)255; return r; };
  float*  h    =(float*)carve((size_t)NN*96*4);
  char*   uni  =carve((size_t)NN*96*4);              // union: hid1 fp32 | {hp16, att}
  float*  hid1 =(float*)uni;
  __half* hp16 =(__half*)uni;                         // NN*96*2 = 9.6 MB
  float*  att  =(float*)(uni+(size_t)NN*96*2);        // NN*8*4  = 1.6 MB
  Rec*    rec  =(Rec*)  carve((size_t)EE*32);
  int*    deg  =(int*)  carve((size_t)NN*4);
  int*    off  =(int*)  carve((size_t)(NN+1)*4);
  int*    cur  =(int*)  carve((size_t)NN*4);
  float*  Watt =(float*)carve((size_t)4*96*8*4);
  float*  Mm   =(float*)carve(64*4);
  int*    part =(int*)  carve(64*4);
  float*  t1b  =(float*)carve((size_t)3*NZ*96*4);
  float*  t2b  =(float*)carve((size_t)3*NZ*48*4);

  const int* srcp=eidx;
  const int* dstp=eidx+EE;

  hipMemsetAsync(deg,0,(size_t)NN*4,stream);
  k_deg<<<EE/256,256,0,stream>>>(dstp,deg);
  k_scan1<<<49,256,0,stream>>>(deg,off,part);
  k_scan2<<<1,64,0,stream>>>(part,off,49);
  k_scan3<<<(NN+255)/256,256,0,stream>>>(part,off,cur);
  k_scatter<<<EE/256,256,0,stream>>>(srcp,dstp,eattr,cur,rec);
  k_prepw<<<(4*96*8+64+255)/256,256,0,stream>>>(conv_w,att_src,att_dst,lin_edge,att_edge,Watt,Mm);

  k_mlp1<<<(NN+255)/256,256,0,stream>>>(x,in_w1,in_b1,hid1);
  k_gemm96<<<(NN+63)/64,256,0,stream>>>(hid1,in_w2,in_b2,h);

  for(int l=0;l<4;l++){
    k_gemmM<<<(NN+63)/64,256,0,stream>>>(h,conv_w+(size_t)l*96*96,Watt+(size_t)l*96*8,hp16,att);
    k_agg<<<(NN+15)/16,256,0,stream>>>(hp16,att,h,off,rec,Mm+l*16,
                                       conv_bias+l*96,nsc+l*96,nbi+l*96);
  }

  k_hd1<<<(3*NZ*96+255)/256,256,0,stream>>>(h,zone,
    (const float*)d_in[16],(const float*)d_in[17],
    (const float*)d_in[22],(const float*)d_in[23],
    (const float*)d_in[28],(const float*)d_in[29], t1b);
  k_hd2<<<(3*NZ*48+255)/256,256,0,stream>>>(t1b,
    (const float*)d_in[18],(const float*)d_in[19],
    (const float*)d_in[24],(const float*)d_in[25],
    (const float*)d_in[30],(const float*)d_in[31], t2b);
  k_hd3<<<(NZ*4+255)/256,256,0,stream>>>(t2b,
    (const float*)d_in[20],(const float*)d_in[21],
    (const float*)d_in[26],(const float*)d_in[27],
    (const float*)d_in[32],(const float*)d_in[33], out);
}

// Round 10
// 356.248 us; speedup vs baseline: 1.4248x; 1.0433x over previous
//
#include <hip/hip_runtime.h>
#include <hip/hip_fp16.h>

#define NN 50000
#define EE 800000
#define HIDD 96
#define NZ 384   // BATCH*NUM_ZONES

typedef __attribute__((ext_vector_type(8))) _Float16 half8;
typedef __attribute__((ext_vector_type(4))) float floatx4;

struct __align__(16) Rec{ int src; __half2 e01; __half2 e23; int pad; };   // 16 B

// ---------- CSR build ----------
__global__ void k_deg(const int* __restrict__ dst, int* __restrict__ deg){
  int e=blockIdx.x*blockDim.x+threadIdx.x;
  if(e>=EE) return;
  atomicAdd(&deg[dst[e]],1);
}

__global__ void k_scan1(const int* __restrict__ deg, int* __restrict__ off, int* __restrict__ part){
  __shared__ int sd[256];
  int t=threadIdx.x, b=blockIdx.x;
  int base=b*1024+t*4;
  int v0=(base+0<NN)?deg[base+0]:0;
  int v1=(base+1<NN)?deg[base+1]:0;
  int v2=(base+2<NN)?deg[base+2]:0;
  int v3=(base+3<NN)?deg[base+3]:0;
  int s=v0+v1+v2+v3;
  sd[t]=s; __syncthreads();
  for(int o=1;o<256;o<<=1){
    int x=(t>=o)?sd[t-o]:0;
    __syncthreads();
    sd[t]+=x;
    __syncthreads();
  }
  int ep=sd[t]-s;
  if(base+0<NN) off[base+0]=ep;
  if(base+1<NN) off[base+1]=ep+v0;
  if(base+2<NN) off[base+2]=ep+v0+v1;
  if(base+3<NN) off[base+3]=ep+v0+v1+v2;
  if(t==255) part[b]=sd[255];
}

__global__ void k_scan2(int* part, int* off, int nb){
  if(threadIdx.x==0&&blockIdx.x==0){
    int run=0;
    for(int i=0;i<nb;i++){ int x=part[i]; part[i]=run; run+=x; }
    off[NN]=run;
  }
}

__global__ void k_scan3(const int* __restrict__ part, int* __restrict__ off, int* __restrict__ cur){
  int i=blockIdx.x*blockDim.x+threadIdx.x;
  if(i<NN){ int v=off[i]+part[i>>10]; off[i]=v; cur[i]=v; }
}

// scatter ONE 16B record per edge: {src, fp16 edge_attr}
__global__ void k_scatter(const int* __restrict__ src, const int* __restrict__ dst,
                          const float* __restrict__ eattr, int* __restrict__ cur,
                          Rec* __restrict__ rec){
  int e=blockIdx.x*blockDim.x+threadIdx.x;
  if(e>=EE) return;
  int d=dst[e];
  int p=atomicAdd(&cur[d],1);
  float4 ea=*(const float4*)(eattr+(size_t)e*4);
  Rec r; r.src=src[e];
  r.e01=__floats2half2_rn(ea.x,ea.y);
  r.e23=__floats2half2_rn(ea.z,ea.w);
  r.pad=0;
  rec[p]=r;
}

// ---------- weight prep: Watt[l][96][8] fp32, M = We.a_edge ----------
__global__ void k_prepw(const float* __restrict__ conv_w, const float* __restrict__ a_src,
                        const float* __restrict__ a_dst, const float* __restrict__ lin_e,
                        const float* __restrict__ a_e,
                        float* __restrict__ Watt, float* __restrict__ Mm){
  int t=blockIdx.x*blockDim.x+threadIdx.x;
  const int WT=4*96*8;
  if(t<WT){
    int l=t/(96*8); int rem=t-l*(96*8); int k=rem>>3; int j=rem&7;
    int hh=j&3;
    const float* W=conv_w+(size_t)l*96*96+(size_t)k*96;
    const float* a=((j>=4)?a_dst:a_src)+l*96+hh*24;
    float v=0.f;
    #pragma unroll
    for(int c=0;c<24;c++) v+=W[hh*24+c]*a[c];
    Watt[t]=v;
  } else if(t<WT+64){
    int q=t-WT; int l=q>>4; int i=(q>>2)&3; int hh=q&3;
    const float* We=lin_e+(size_t)l*4*96+(size_t)i*96;
    const float* a=a_e+l*96+hh*24;
    float v=0.f;
    #pragma unroll
    for(int c=0;c<24;c++) v+=We[hh*24+c]*a[c];
    Mm[q]=v;  // M[l][i][h]
  }
}

// ---------- fused input MLP: h = relu(x@w1+b1)@w2 + b2 ----------
__global__ __launch_bounds__(256) void k_gemm96(const float* __restrict__ x,
                                                const float* __restrict__ w1,
                                                const float* __restrict__ b1,
                                                const float* __restrict__ W,
                                                const float* __restrict__ bias,
                                                float* __restrict__ C){
  __shared__ float As[64][100];
  __shared__ float Ws[96][96];
  __shared__ float b1s[96];
  int t=threadIdx.x;
  int r0=blockIdx.x*64;
  // phase A: w1 into Ws region, compute As = relu(x@w1+b1)
  for(int i=t;i<12*96/4;i+=256) ((float4*)&Ws[0][0])[i]=((const float4*)w1)[i];
  if(t<96) b1s[t]=b1[t];
  __syncthreads();
  {
    int r=t>>2, cq=t&3;
    int g=r0+r;
    float xv[12];
    if(g<NN){
      float4 v0=*(const float4*)(x+(size_t)g*12);
      float4 v1=*(const float4*)(x+(size_t)g*12+4);
      float4 v2=*(const float4*)(x+(size_t)g*12+8);
      xv[0]=v0.x;xv[1]=v0.y;xv[2]=v0.z;xv[3]=v0.w;
      xv[4]=v1.x;xv[5]=v1.y;xv[6]=v1.z;xv[7]=v1.w;
      xv[8]=v2.x;xv[9]=v2.y;xv[10]=v2.z;xv[11]=v2.w;
    }else{
      #pragma unroll
      for(int k=0;k<12;k++) xv[k]=0.f;
    }
    const float* w1f=&Ws[0][0];
    #pragma unroll
    for(int j=0;j<24;j++){
      int c=cq+4*j;
      float a=b1s[c];
      #pragma unroll
      for(int k=0;k<12;k++) a+=xv[k]*w1f[k*96+c];
      As[r][c]=fmaxf(a,0.f);
    }
  }
  __syncthreads();
  // phase B: load w2, main GEMM
  for(int i=t;i<96*96/4;i+=256) ((float4*)&Ws[0][0])[i]=((const float4*)W)[i];
  __syncthreads();
  int cg=t&15, rg=t>>4;
  int c0=cg*6, r=rg*4;
  float acc[4][6];
  #pragma unroll
  for(int i=0;i<4;i++)
    #pragma unroll
    for(int j=0;j<6;j++) acc[i][j]=0.f;
  for(int k4=0;k4<96;k4+=4){
    float4 a0=*(float4*)&As[r  ][k4];
    float4 a1=*(float4*)&As[r+1][k4];
    float4 a2=*(float4*)&As[r+2][k4];
    float4 a3=*(float4*)&As[r+3][k4];
    #pragma unroll
    for(int kk=0;kk<4;kk++){
      float2 w01=*(float2*)&Ws[k4+kk][c0];
      float2 w23=*(float2*)&Ws[k4+kk][c0+2];
      float2 w45=*(float2*)&Ws[k4+kk][c0+4];
      float wv[6]={w01.x,w01.y,w23.x,w23.y,w45.x,w45.y};
      float av0=((float*)&a0)[kk],av1=((float*)&a1)[kk],av2=((float*)&a2)[kk],av3=((float*)&a3)[kk];
      #pragma unroll
      for(int j=0;j<6;j++){
        acc[0][j]+=av0*wv[j];
        acc[1][j]+=av1*wv[j];
        acc[2][j]+=av2*wv[j];
        acc[3][j]+=av3*wv[j];
      }
    }
  }
  #pragma unroll
  for(int i=0;i<4;i++){
    int g=r0+r+i;
    if(g<NN){
      #pragma unroll
      for(int j=0;j<6;j++) C[(size_t)g*96+c0+j]=acc[i][j]+bias[c0+j];
    }
  }
}

// ---------- MFMA projection GEMM: [hp16 | att] = A[N][96] @ [W 96x96 | Watt 96x8] ----------
__global__ __launch_bounds__(256) void k_gemmM(const float* __restrict__ A,
    const float* __restrict__ W, const float* __restrict__ Watt8,
    __half* __restrict__ hp16, float* __restrict__ att){
  __shared__ half8 Bl[3][7][64];   // 21504 B, pre-swizzled to fragment layout
  int t=threadIdx.x;
  for(int i=t;i<3*7*64;i+=256){
    int kk=i/448; int rem=i-kk*448; int nb=rem>>6; int l=rem&63;
    int kbase=kk*32+((l>>4)<<3);
    int n=nb*16+(l&15);
    half8 v;
    #pragma unroll
    for(int j=0;j<8;j++){
      int k=kbase+j;
      float x=(n<96)?W[k*96+n]:((n<104)?Watt8[k*8+(n-96)]:0.f);
      v[j]=(_Float16)x;
    }
    Bl[kk][nb][l]=v;
  }
  __syncthreads();
  int wid=t>>6, l=t&63;
  int row0=blockIdx.x*64+wid*16;
  int arow=row0+(l&15);
  bool rv=arow<NN;
  const float* Ar=A+(size_t)(rv?arow:0)*96;
  half8 a[3];
  #pragma unroll
  for(int kk=0;kk<3;kk++){
    int kb=kk*32+((l>>4)<<3);
    floatx4 lo=*(const floatx4*)(Ar+kb);
    floatx4 hi=*(const floatx4*)(Ar+kb+4);
    half8 v;
    #pragma unroll
    for(int j=0;j<4;j++){ v[j]=(_Float16)(rv?lo[j]:0.f); v[j+4]=(_Float16)(rv?hi[j]:0.f); }
    a[kk]=v;
  }
  int col16=l&15;
  int rbase=row0+((l>>4)<<2);
  #pragma unroll
  for(int nb=0;nb<7;nb++){
    floatx4 acc={0.f,0.f,0.f,0.f};
    #pragma unroll
    for(int kk=0;kk<3;kk++)
      acc=__builtin_amdgcn_mfma_f32_16x16x32_f16(a[kk],Bl[kk][nb][l],acc,0,0,0);
    int col=nb*16+col16;
    if(col<96){
      #pragma unroll
      for(int r=0;r<4;r++){
        int g=rbase+r;
        if(g<NN) hp16[(size_t)g*96+col]=__float2half(acc[r]);
      }
    } else if(col<104){
      #pragma unroll
      for(int r=0;r<4;r++){
        int g=rbase+r;
        if(g<NN) att[(size_t)g*8+(col-96)]=acc[r];
      }
    }
  }
}

// ---------- fused GAT agg (no-max softmax) + self-loop + bias + ELU + residual + LN ----------
// 16-lane subgroup per node; block = 256 threads = 16 nodes.
__global__ __launch_bounds__(256) void k_agg(const __half* __restrict__ hp16,
    const float* __restrict__ att, float* __restrict__ h,
    const int* __restrict__ off, const Rec* __restrict__ rec,
    const float* __restrict__ Mm, const float* __restrict__ bias,
    const float* __restrict__ nsc, const float* __restrict__ nbi){
  __shared__ float w4[16][17][4];
  __shared__ int   roA[16][17];
  int tid=threadIdx.x;
  int sg=tid>>4, sl=tid&15;
  int n=blockIdx.x*16+sg;
  if(n>=NN) return;
  float M[16];
  #pragma unroll
  for(int i=0;i<16;i++) M[i]=Mm[i];
  const float4 ad=*(const float4*)(att+(size_t)n*8+4);
  int b0=off[n], deg=off[n+1]-b0;
  float invdeg=1.f/(float)(deg>0?deg:1);
  int hL=sl>>2;
  int sloff=sl*12;
  float ds0=0.f,ds1=0.f,ds2=0.f,ds3=0.f;
  float sx=0.f,sy=0.f,sz=0.f,sw=0.f;
  float acc[6]={0.f,0.f,0.f,0.f,0.f,0.f};
  const char* hb=(const char*)hp16;

  for(int cs=0;cs<deg;cs+=16){
    int idx=cs+sl;
    bool valid=idx<deg;
    float w0=0.f,w1=0.f,w2=0.f,w3=0.f; int ro=0;
    if(valid){
      int ei=b0+idx;
      Rec rr=rec[ei];
      int s=rr.src;
      float2 e01=__half22float2(rr.e01);
      float2 e23=__half22float2(rr.e23);
      ro=s*192;
      sx+=e01.x; sy+=e01.y; sz+=e23.x; sw+=e23.y;
      const float4 as=*(const float4*)(att+(size_t)s*8);
      float a0=as.x+ad.x+e01.x*M[0]+e01.y*M[4]+e23.x*M[8] +e23.y*M[12];
      float a1=as.y+ad.y+e01.x*M[1]+e01.y*M[5]+e23.x*M[9] +e23.y*M[13];
      float a2=as.z+ad.z+e01.x*M[2]+e01.y*M[6]+e23.x*M[10]+e23.y*M[14];
      float a3=as.w+ad.w+e01.x*M[3]+e01.y*M[7]+e23.x*M[11]+e23.y*M[15];
      a0=a0>0.f?a0:0.2f*a0; a1=a1>0.f?a1:0.2f*a1;
      a2=a2>0.f?a2:0.2f*a2; a3=a3>0.f?a3:0.2f*a3;
      w0=__expf(a0); w1=__expf(a1); w2=__expf(a2); w3=__expf(a3);
      ds0+=w0; ds1+=w1; ds2+=w2; ds3+=w3;
    }
    *(float4*)&w4[sg][sl][0]=float4{w0,w1,w2,w3};
    roA[sg][sl]=ro;
    int nc=deg-cs; if(nc>16) nc=16;
    if(nc>0){
      float ev0=w4[sg][0][hL];
      uint3 u0=*(const uint3*)(hb+(size_t)(unsigned)roA[sg][0]+sloff);
      for(int j=1;j<nc;j++){
        float ev1=w4[sg][j][hL];
        uint3 u1=*(const uint3*)(hb+(size_t)(unsigned)roA[sg][j]+sloff);
        float2 f0=__half22float2(*(__half2*)&u0.x);
        float2 f1=__half22float2(*(__half2*)&u0.y);
        float2 f2=__half22float2(*(__half2*)&u0.z);
        acc[0]+=ev0*f0.x; acc[1]+=ev0*f0.y;
        acc[2]+=ev0*f1.x; acc[3]+=ev0*f1.y;
        acc[4]+=ev0*f2.x; acc[5]+=ev0*f2.y;
        ev0=ev1; u0=u1;
      }
      float2 f0=__half22float2(*(__half2*)&u0.x);
      float2 f1=__half22float2(*(__half2*)&u0.y);
      float2 f2=__half22float2(*(__half2*)&u0.z);
      acc[0]+=ev0*f0.x; acc[1]+=ev0*f0.y;
      acc[2]+=ev0*f1.x; acc[3]+=ev0*f1.y;
      acc[4]+=ev0*f2.x; acc[5]+=ev0*f2.y;
    }
  }
  // 16-lane reductions (denominators + edge-attr sums)
  #pragma unroll
  for(int m=1;m<16;m<<=1){
    ds0+=__shfl_xor(ds0,m); ds1+=__shfl_xor(ds1,m);
    ds2+=__shfl_xor(ds2,m); ds3+=__shfl_xor(ds3,m);
    sx +=__shfl_xor(sx ,m); sy +=__shfl_xor(sy ,m);
    sz +=__shfl_xor(sz ,m); sw +=__shfl_xor(sw ,m);
  }
  // self-loop with mean edge-attr
  float lx=sx*invdeg, ly=sy*invdeg, lz=sz*invdeg, lw=sw*invdeg;
  const float4 aself=*(const float4*)(att+(size_t)n*8);
  float b0a=aself.x+ad.x+lx*M[0]+ly*M[4]+lz*M[8] +lw*M[12];
  float b1a=aself.y+ad.y+lx*M[1]+ly*M[5]+lz*M[9] +lw*M[13];
  float b2a=aself.z+ad.z+lx*M[2]+ly*M[6]+lz*M[10]+lw*M[14];
  float b3a=aself.w+ad.w+lx*M[3]+ly*M[7]+lz*M[11]+lw*M[15];
  b0a=b0a>0.f?b0a:0.2f*b0a; b1a=b1a>0.f?b1a:0.2f*b1a;
  b2a=b2a>0.f?b2a:0.2f*b2a; b3a=b3a>0.f?b3a:0.2f*b3a;
  float e0=__expf(b0a),e1=__expf(b1a),e2=__expf(b2a),e3=__expf(b3a);
  ds0+=e0; ds1+=e1; ds2+=e2; ds3+=e3;
  float eL=(hL==0)?e0:((hL==1)?e1:((hL==2)?e2:e3));
  {
    const char* rp=hb+(size_t)n*192+sloff;
    uint3 u=*(const uint3*)rp;
    float2 f0=__half22float2(*(__half2*)&u.x);
    float2 f1=__half22float2(*(__half2*)&u.y);
    float2 f2=__half22float2(*(__half2*)&u.z);
    acc[0]+=eL*f0.x; acc[1]+=eL*f0.y;
    acc[2]+=eL*f1.x; acc[3]+=eL*f1.y;
    acc[4]+=eL*f2.x; acc[5]+=eL*f2.y;
  }
  // epilogue: /den + bias -> ELU -> +residual -> LayerNorm (16-lane)
  float dL=(hL==0)?ds0:((hL==1)?ds1:((hL==2)?ds2:ds3));
  float rinv=1.f/(dL+1e-16f);
  const float* hrow=h+(size_t)n*HIDD+(size_t)sl*6;
  float2 r01=*(const float2*)(hrow);
  float2 r23=*(const float2*)(hrow+2);
  float2 r45=*(const float2*)(hrow+4);
  float rr[6]={r01.x,r01.y,r23.x,r23.y,r45.x,r45.y};
  const float* bp=bias+sl*6;
  float t[6];
  #pragma unroll
  for(int c=0;c<6;c++){
    float v=acc[c]*rinv+bp[c];
    v=v>0.f?v:expm1f(v);
    t[c]=v+rr[c];
  }
  float s1l=t[0]+t[1]+t[2]+t[3]+t[4]+t[5];
  float s2l=t[0]*t[0]+t[1]*t[1]+t[2]*t[2]+t[3]*t[3]+t[4]*t[4]+t[5]*t[5];
  #pragma unroll
  for(int m=1;m<16;m<<=1){ s1l+=__shfl_xor(s1l,m); s2l+=__shfl_xor(s2l,m); }
  float mean=s1l*(1.f/96.f);
  float var=s2l*(1.f/96.f)-mean*mean;
  float rs=rsqrtf(var+1e-5f);
  float* op=h+(size_t)n*HIDD+(size_t)sl*6;
  const float* sc=nsc+sl*6;
  const float* bi=nbi+sl*6;
  float o[6];
  #pragma unroll
  for(int c=0;c<6;c++) o[c]=(t[c]-mean)*rs*sc[c]+bi[c];
  *(float2*)(op)  =float2{o[0],o[1]};
  *(float2*)(op+2)=float2{o[2],o[3]};
  *(float2*)(op+4)=float2{o[4],o[5]};
}

// ---------- prediction heads ----------
__global__ __launch_bounds__(256) void k_hd1(const float* __restrict__ h, const int* __restrict__ zone,
    const float* __restrict__ cw1,const float* __restrict__ cb1,
    const float* __restrict__ dw1,const float* __restrict__ db1,
    const float* __restrict__ jw1,const float* __restrict__ jb1,
    float* __restrict__ t1){
  int idx=blockIdx.x*256+threadIdx.x;
  if(idx>=3*NZ*96) return;
  int hd=idx/(NZ*96); int rem=idx-hd*(NZ*96); int row=rem/96; int j=rem-row*96;
  const float* w1=(hd==0)?cw1:((hd==1)?dw1:jw1);
  const float* b1=(hd==0)?cb1:((hd==1)?db1:jb1);
  int n=zone[row];
  const float* hr=h+(size_t)n*96;
  float acc=b1[j];
  #pragma unroll
  for(int k4=0;k4<24;k4++){
    float4 hv=*(const float4*)(hr+k4*4);
    acc+=hv.x*w1[(k4*4+0)*96+j];
    acc+=hv.y*w1[(k4*4+1)*96+j];
    acc+=hv.z*w1[(k4*4+2)*96+j];
    acc+=hv.w*w1[(k4*4+3)*96+j];
  }
  t1[idx]=fmaxf(acc,0.f);
}

__global__ __launch_bounds__(256) void k_hd2(const float* __restrict__ t1,
    const float* __restrict__ cw2,const float* __restrict__ cb2,
    const float* __restrict__ dw2,const float* __restrict__ db2,
    const float* __restrict__ jw2,const float* __restrict__ jb2,
    float* __restrict__ t2){
  int idx=blockIdx.x*256+threadIdx.x;
  if(idx>=3*NZ*48) return;
  int hd=idx/(NZ*48); int rem=idx-hd*(NZ*48); int row=rem/48; int c=rem-row*48;
  const float* w2=(hd==0)?cw2:((hd==1)?dw2:jw2);
  const float* b2=(hd==0)?cb2:((hd==1)?db2:jb2);
  const float* t1r=t1+(size_t)hd*NZ*96+(size_t)row*96;
  float acc=b2[c];
  #pragma unroll
  for(int k4=0;k4<24;k4++){
    float4 tv=*(const float4*)(t1r+k4*4);
    acc+=tv.x*w2[(k4*4+0)*48+c];
    acc+=tv.y*w2[(k4*4+1)*48+c];
    acc+=tv.z*w2[(k4*4+2)*48+c];
    acc+=tv.w*w2[(k4*4+3)*48+c];
  }
  t2[idx]=fmaxf(acc,0.f);
}

__global__ __launch_bounds__(256) void k_hd3(const float* __restrict__ t2,
    const float* __restrict__ cw3,const float* __restrict__ cb3,
    const float* __restrict__ dw3,const float* __restrict__ db3,
    const float* __restrict__ jw3,const float* __restrict__ jb3,
    float* __restrict__ out){
  int idx=blockIdx.x*256+threadIdx.x;
  if(idx>=NZ*4) return;
  int row=idx>>2, o=idx&3;
  int hd=(o<2)?0:((o==2)?1:2);
  int c=(o<2)?o:0;
  int osz=(hd==0)?2:1;
  const float* w3=(hd==0)?cw3:((hd==1)?dw3:jw3);
  const float* b3=(hd==0)?cb3:((hd==1)?db3:jb3);
  const float* t2r=t2+(size_t)hd*NZ*48+(size_t)row*48;
  float acc=b3[c];
  #pragma unroll
  for(int k=0;k<48;k++) acc+=t2r[k]*w3[k*osz+c];
  out[idx]=acc;
}

extern "C" void kernel_launch(void* const* d_in, const int* in_sizes, int n_in,
                              void* d_out, int out_size, void* d_ws, size_t ws_size,
                              hipStream_t stream){
  const float* x       =(const float*)d_in[0];
  const int*   eidx    =(const int*)  d_in[1];
  const float* eattr   =(const float*)d_in[2];
  const int*   zone    =(const int*)  d_in[3];
  const float* in_w1   =(const float*)d_in[4];
  const float* in_b1   =(const float*)d_in[5];
  const float* in_w2   =(const float*)d_in[6];
  const float* in_b2   =(const float*)d_in[7];
  const float* conv_w  =(const float*)d_in[8];
  const float* att_src =(const float*)d_in[9];
  const float* att_dst =(const float*)d_in[10];
  const float* lin_edge=(const float*)d_in[11];
  const float* att_edge=(const float*)d_in[12];
  const float* conv_bias=(const float*)d_in[13];
  const float* nsc     =(const float*)d_in[14];
  const float* nbi     =(const float*)d_in[15];
  float* out=(float*)d_out;

  char* p=(char*)d_ws;
  auto carve=[&](size_t bytes)->char*{ char* r=p; p+=(bytes+255)&~(size_t)255; return r; };
  float*  h    =(float*)carve((size_t)NN*96*4);
  char*   uni  =carve((size_t)NN*96*4);              // union: {hp16, att}
  __half* hp16 =(__half*)uni;                         // NN*96*2 = 9.6 MB
  float*  att  =(float*)(uni+(size_t)NN*96*2);        // NN*8*4  = 1.6 MB
  Rec*    rec  =(Rec*)  carve((size_t)EE*16);
  int*    deg  =(int*)  carve((size_t)NN*4);
  int*    off  =(int*)  carve((size_t)(NN+1)*4);
  int*    cur  =(int*)  carve((size_t)NN*4);
  float*  Watt =(float*)carve((size_t)4*96*8*4);
  float*  Mm   =(float*)carve(64*4);
  int*    part =(int*)  carve(64*4);
  float*  t1b  =(float*)carve((size_t)3*NZ*96*4);
  float*  t2b  =(float*)carve((size_t)3*NZ*48*4);

  const int* srcp=eidx;
  const int* dstp=eidx+EE;

  hipMemsetAsync(deg,0,(size_t)NN*4,stream);
  k_deg<<<EE/256,256,0,stream>>>(dstp,deg);
  k_scan1<<<49,256,0,stream>>>(deg,off,part);
  k_scan2<<<1,64,0,stream>>>(part,off,49);
  k_scan3<<<(NN+255)/256,256,0,stream>>>(part,off,cur);
  k_scatter<<<EE/256,256,0,stream>>>(srcp,dstp,eattr,cur,rec);
  k_prepw<<<(4*96*8+64+255)/256,256,0,stream>>>(conv_w,att_src,att_dst,lin_edge,att_edge,Watt,Mm);

  k_gemm96<<<(NN+63)/64,256,0,stream>>>(x,in_w1,in_b1,in_w2,in_b2,h);

  for(int l=0;l<4;l++){
    k_gemmM<<<(NN+63)/64,256,0,stream>>>(h,conv_w+(size_t)l*96*96,Watt+(size_t)l*96*8,hp16,att);
    k_agg<<<(NN+15)/16,256,0,stream>>>(hp16,att,h,off,rec,Mm+l*16,
                                       conv_bias+l*96,nsc+l*96,nbi+l*96);
  }

  k_hd1<<<(3*NZ*96+255)/256,256,0,stream>>>(h,zone,
    (const float*)d_in[16],(const float*)d_in[17],
    (const float*)d_in[22],(const float*)d_in[23],
    (const float*)d_in[28],(const float*)d_in[29], t1b);
  k_hd2<<<(3*NZ*48+255)/256,256,0,stream>>>(t1b,
    (const float*)d_in[18],(const float*)d_in[19],
    (const float*)d_in[24],(const float*)d_in[25],
    (const float*)d_in[30],(const float*)d_in[31], t2b);
  k_hd3<<<(NZ*4+255)/256,256,0,stream>>>(t2b,
    (const float*)d_in[20],(const float*)d_in[21],
    (const float*)d_in[26],(const float*)d_in[27],
    (const float*)d_in[32],(const float*)d_in[33], out);
}